// Round 10
// baseline (58.807 us; speedup 1.0000x reference)
//
#include <hip/hip_runtime.h>
#include <math.h>

#define HN 1024
#define VN 50257
#define SN 8192

// ws layout (float offsets)
#define WS_PARTIAL 0          // 8*1024: per-rowchunk column partial sums
#define WS_X       8192       // 1024: relu(combined)
#define WS_GH      9216       // 3072: raw w_hh @ h0
#define WS_CEMB    12288      // 1024: comb_w[:, :H] @ emb + comb_b
#define WS_HNEW    13312      // 1024: h_new
#define WS_LOGITS  14336      // 50257
#define WS_EXPD    64594      // 2112 doubles (8B-aligned: 64594*4 % 8 == 0)

__device__ __forceinline__ float wred(float v) {
#pragma unroll
  for (int m = 32; m; m >>= 1) v += __shfl_xor(v, m);
  return v;
}

__device__ __forceinline__ float dot4(float4 a, float4 b) {
  return a.x * b.x + a.y * b.y + a.z * b.z + a.w * b.w;
}

__device__ __forceinline__ float4 f4add(float4 a, float4 b) {
  return make_float4(a.x + b.x, a.y + b.y, a.z + b.z, a.w + b.w);
}

// K1 (256 blocks x 1024 thr), uniform ~136 KB/block, float4 loads:
//   phase A: block (chunk=blk>>5, stripe=blk&31) sums rows [chunk*1024,+1024)
//            over cols [stripe*32,+32). Thread (slot=t>>3, col4=t&7) reads 8
//            float4s (rows slot+j*128) -> LDS tree over 128 slots ->
//            partial[chunk][stripe*32..+32]. 1KB/wave-instr coalescing.
//   phase B: waves 0-3: cemb row blk*4+w = comb_w[i,:H] @ emb + comb_b[i]
__global__ __launch_bounds__(1024) void k1_front(
    const float* __restrict__ enc, const int* __restrict__ token,
    const float* __restrict__ embedding, const float* __restrict__ comb_w,
    const float* __restrict__ comb_b, float* __restrict__ ws,
    float* __restrict__ out_attn) {
  const int blk = blockIdx.x, t = threadIdx.x;
  __shared__ float4 lds4[1024];
  const int chunk = blk >> 5, stripe = blk & 31;
  {
    const int slot = t >> 3, col4 = t & 7;
    const float4* base = (const float4*)enc +
                         ((size_t)chunk * 1024 + slot) * 256 + stripe * 8 + col4;
    float4 acc = make_float4(0.f, 0.f, 0.f, 0.f);
#pragma unroll
    for (int j = 0; j < 8; ++j) acc = f4add(acc, base[j * 128 * 256]);
    lds4[t] = acc;  // index = slot*8 + col4
  }
  __syncthreads();
  if (t < 512) lds4[t] = f4add(lds4[t], lds4[t + 512]);
  __syncthreads();
  if (t < 256) lds4[t] = f4add(lds4[t], lds4[t + 256]);
  __syncthreads();
  if (t < 128) lds4[t] = f4add(lds4[t], lds4[t + 128]);
  __syncthreads();
  if (t < 64) lds4[t] = f4add(lds4[t], lds4[t + 64]);
  __syncthreads();
  if (t < 32) lds4[t] = f4add(lds4[t], lds4[t + 32]);
  __syncthreads();
  if (t < 16) lds4[t] = f4add(lds4[t], lds4[t + 16]);
  __syncthreads();
  if (t < 8) {
    float4 s = f4add(lds4[t], lds4[t + 8]);
    ((float4*)(ws + WS_PARTIAL))[chunk * 256 + stripe * 8 + t] = s;
  }
  if (t < 32) out_attn[blk * 32 + t] = 1.f / 8192.f;  // softmax(const) exact
  const int w = t >> 6, l = t & 63;
  if (w < 4) {
    const int i = blk * 4 + w;  // 0..1023
    const int tok = token[0];
    const float4* emb4 = (const float4*)embedding + (size_t)tok * 256;
    const float4* cw4 = (const float4*)comb_w + (size_t)i * 512;  // first half
    float acc = dot4(cw4[l], emb4[l]) + dot4(cw4[64 + l], emb4[64 + l]) +
                dot4(cw4[128 + l], emb4[128 + l]) + dot4(cw4[192 + l], emb4[192 + l]);
    acc = wred(acc);
    if (l == 0) ws[WS_CEMB + i] = acc + comb_b[i];
  }
}

// K2 (256 blocks x 1024): block-specialized:
//   blk<192 : gh row r = blk*16 + w  (one 4KB row per wave)
//   192..255: x rows — block redundantly reduces the 8 column-partials
//             (32 KB L2) into LDS aa, then 16 waves each do one row:
//             x[i] = relu(cemb[i] + comb_w[i, H:] @ aa)
__global__ __launch_bounds__(1024) void k2_mid(
    const float* __restrict__ w_hh, const float* __restrict__ hidden,
    const float* __restrict__ comb_w, float* __restrict__ ws) {
  const int blk = blockIdx.x, t = threadIdx.x;
  const int w = t >> 6, l = t & 63;
  if (blk < 192) {
    const int r = blk * 16 + w;  // 0..3071
    const float4* h4 = (const float4*)hidden;
    const float4* m4 = (const float4*)w_hh + (size_t)r * 256;
    float acc = dot4(m4[l], h4[l]) + dot4(m4[64 + l], h4[64 + l]) +
                dot4(m4[128 + l], h4[128 + l]) + dot4(m4[192 + l], h4[192 + l]);
    acc = wred(acc);
    if (l == 0) ws[WS_GH + r] = acc;
  } else {
    __shared__ float aas[1024];
    float s = 0.f;
#pragma unroll
    for (int j = 0; j < 8; ++j) s += ws[WS_PARTIAL + j * 1024 + t];
    aas[t] = s * (1.f / 8192.f);
    __syncthreads();
    const int i = (blk - 192) * 16 + w;  // 0..1023
    const float4* aa4 = (const float4*)aas;
    const float4* cw4 = (const float4*)comb_w + (size_t)i * 512 + 256;  // 2nd half
    float acc = dot4(cw4[l], aa4[l]) + dot4(cw4[64 + l], aa4[64 + l]) +
                dot4(cw4[128 + l], aa4[128 + l]) + dot4(cw4[192 + l], aa4[192 + l]);
    acc = wred(acc);
    if (l == 0) ws[WS_X + i] = fmaxf(ws[WS_CEMB + i] + acc, 0.f);
  }
}

// K4 (256 blocks x 256): wave computes all 3 gi rows for its i, then lane 0
// applies GRU gate math -> h_new.
__global__ void k4_gates_h(const float* __restrict__ w_ih,
                           const float* __restrict__ b_ih, const float* __restrict__ b_hh,
                           const float* __restrict__ hidden, float* __restrict__ ws,
                           float* __restrict__ d_out) {
  const int w = threadIdx.x >> 6, l = threadIdx.x & 63;
  const int i = blockIdx.x * 4 + w;  // 0..1023
  const float4* x4 = (const float4*)(ws + WS_X);
  float4 xv0 = x4[l], xv1 = x4[64 + l], xv2 = x4[128 + l], xv3 = x4[192 + l];
  const float4* m0 = (const float4*)w_ih + (size_t)i * 256;
  const float4* m1 = (const float4*)w_ih + (size_t)(i + 1024) * 256;
  const float4* m2 = (const float4*)w_ih + (size_t)(i + 2048) * 256;
  float a0 = dot4(m0[l], xv0) + dot4(m0[64 + l], xv1) +
             dot4(m0[128 + l], xv2) + dot4(m0[192 + l], xv3);
  float a1 = dot4(m1[l], xv0) + dot4(m1[64 + l], xv1) +
             dot4(m1[128 + l], xv2) + dot4(m1[192 + l], xv3);
  float a2 = dot4(m2[l], xv0) + dot4(m2[64 + l], xv1) +
             dot4(m2[128 + l], xv2) + dot4(m2[192 + l], xv3);
  a0 = wred(a0); a1 = wred(a1); a2 = wred(a2);
  if (l == 0) {
    float ir = a0 + b_ih[i];
    float iz = a1 + b_ih[i + 1024];
    float inn = a2 + b_ih[i + 2048];
    float hr = ws[WS_GH + i] + b_hh[i];
    float hz = ws[WS_GH + i + 1024] + b_hh[i + 1024];
    float hn = ws[WS_GH + i + 2048] + b_hh[i + 2048];
    float rg = 1.f / (1.f + expf(-(ir + hr)));
    float zg = 1.f / (1.f + expf(-(iz + hz)));
    float ng = tanhf(inn + rg * hn);
    float h = (1.f - zg) * ng + zg * hidden[i];
    ws[WS_HNEW + i] = h;
    d_out[VN + i] = h;  // h_new output region
  }
}

// K5 (2112 blocks x 256 = 8448 waves): logits GEMV, 6 CONSECUTIVE rows per
// wave (24KB contiguous; 24 independent dwordx4 loads in flight). Tail waves
// clamp addresses (wave-uniform) and predicate stores. Per-block exp partials
// in fixed order (deterministic).
__global__ void k5_logits(const float* __restrict__ out_w, const float* __restrict__ out_b,
                          float* __restrict__ ws) {
  const int blk = blockIdx.x, t = threadIdx.x;
  const int w = t >> 6, l = t & 63;
  const int gw = blk * 4 + w;       // 0..8447
  const int base = gw * 6;          // rows [base, base+6)
  const float4* h4p = (const float4*)(ws + WS_HNEW);
  float4 h0_ = h4p[l], h1_ = h4p[64 + l], h2_ = h4p[128 + l], h3_ = h4p[192 + l];
  const float4* ow4 = (const float4*)out_w;
  float a[6];
#pragma unroll
  for (int r = 0; r < 6; ++r) {
    const int v = base + r;
    const int vc = (v < VN) ? v : (VN - 1);  // clamp: loads stay in-bounds
    const float4* p = ow4 + (size_t)vc * 256;
    a[r] = dot4(p[l], h0_) + dot4(p[64 + l], h1_) +
           dot4(p[128 + l], h2_) + dot4(p[192 + l], h3_);
  }
#pragma unroll
  for (int r = 0; r < 6; ++r) a[r] = wred(a[r]);
  double eacc = 0.0;
  if (l == 0) {
#pragma unroll
    for (int r = 0; r < 6; ++r) {
      const int v = base + r;
      if (v < VN) {
        float lg = a[r] + out_b[v];
        ws[WS_LOGITS + v] = lg;
        eacc += (double)expf(lg);  // |logit| small: no max-subtract needed
      }
    }
  }
  __shared__ double sd[4];
  if (l == 0) sd[w] = eacc;
  __syncthreads();
  if (t == 0) ((double*)(ws + WS_EXPD))[blk] = sd[0] + sd[1] + sd[2] + sd[3];
}

// K6: redundant deterministic logZ (fixed-order reduce of 2112 doubles) + subtract
__global__ void k6_final(const float* __restrict__ ws, float* __restrict__ d_out) {
  __shared__ double sd[256];
  const int t = threadIdx.x;
  const double* ed = (const double*)(ws + WS_EXPD);
  double a = 0.0;
#pragma unroll
  for (int j = 0; j < 8; ++j) a += ed[t + j * 256];
  if (t < 64) a += ed[t + 2048];
  sd[t] = a;
  __syncthreads();
  for (int s = 128; s; s >>= 1) {
    if (t < s) sd[t] += sd[t + s];
    __syncthreads();
  }
  const float logZ = (float)log(sd[0]);
  const int v = blockIdx.x * 256 + t;
  if (v < VN) d_out[v] = ws[WS_LOGITS + v] - logZ;
}

extern "C" void kernel_launch(void* const* d_in, const int* in_sizes, int n_in,
                              void* d_out, int out_size, void* d_ws, size_t ws_size,
                              hipStream_t stream) {
  const int* token = (const int*)d_in[0];
  const float* hidden = (const float*)d_in[1];
  const float* enc = (const float*)d_in[2];
  const float* embedding = (const float*)d_in[3];
  // d_in[4] attn_w, d_in[5] attn_b unused: softmax(broadcast(scalar)) is uniform
  const float* comb_w = (const float*)d_in[6];
  const float* comb_b = (const float*)d_in[7];
  const float* w_ih = (const float*)d_in[8];
  const float* w_hh = (const float*)d_in[9];
  const float* b_ih = (const float*)d_in[10];
  const float* b_hh = (const float*)d_in[11];
  const float* out_w = (const float*)d_in[12];
  const float* out_b = (const float*)d_in[13];
  float* out = (float*)d_out;
  float* ws = (float*)d_ws;

  k1_front<<<256, 1024, 0, stream>>>(enc, token, embedding, comb_w, comb_b,
                                     ws, out + VN + HN);
  k2_mid<<<256, 1024, 0, stream>>>(w_hh, hidden, comb_w, ws);
  k4_gates_h<<<256, 256, 0, stream>>>(w_ih, b_ih, b_hh, hidden, ws, out);
  k5_logits<<<2112, 256, 0, stream>>>(out_w, out_b, ws);
  k6_final<<<197, 256, 0, stream>>>(ws, out);
}

// Round 11
// 58.174 us; speedup vs baseline: 1.0109x; 1.0109x over previous
//
#include <hip/hip_runtime.h>
#include <math.h>

#define HN 1024
#define VN 50257
#define SN 8192

// ws layout (float offsets)
#define WS_PARTIAL 0          // 8*1024: per-rowchunk column partial sums
#define WS_X       8192       // 1024: relu(combined)
#define WS_GH      9216       // 3072: raw w_hh @ h0
#define WS_CEMB    12288      // 1024: comb_w[:, :H] @ emb + comb_b
#define WS_HNEW    13312      // 1024: h_new
#define WS_LOGITS  14336      // 50257
#define WS_EXPD    64594      // 2048 doubles (8B-aligned: 64594*4 % 8 == 0)

__device__ __forceinline__ float wred(float v) {
#pragma unroll
  for (int m = 32; m; m >>= 1) v += __shfl_xor(v, m);
  return v;
}

__device__ __forceinline__ float dot4(float4 a, float4 b) {
  return a.x * b.x + a.y * b.y + a.z * b.z + a.w * b.w;
}

__device__ __forceinline__ float4 f4add(float4 a, float4 b) {
  return make_float4(a.x + b.x, a.y + b.y, a.z + b.z, a.w + b.w);
}

// K1 (256 blocks x 1024 thr), uniform ~136 KB/block, float4 loads:
//   phase A: block (chunk=blk>>5, stripe=blk&31) sums rows [chunk*1024,+1024)
//            over cols [stripe*32,+32). Thread (slot=t>>3, col4=t&7) reads 8
//            float4s -> LDS tree over 128 slots -> partial[chunk][stripe*32..+32]
//   phase B: waves 0-3: cemb row blk*4+w = comb_w[i,:H] @ emb + comb_b[i]
__global__ __launch_bounds__(1024) void k1_front(
    const float* __restrict__ enc, const int* __restrict__ token,
    const float* __restrict__ embedding, const float* __restrict__ comb_w,
    const float* __restrict__ comb_b, float* __restrict__ ws,
    float* __restrict__ out_attn) {
  const int blk = blockIdx.x, t = threadIdx.x;
  __shared__ float4 lds4[1024];
  const int chunk = blk >> 5, stripe = blk & 31;
  {
    const int slot = t >> 3, col4 = t & 7;
    const float4* base = (const float4*)enc +
                         ((size_t)chunk * 1024 + slot) * 256 + stripe * 8 + col4;
    float4 acc = make_float4(0.f, 0.f, 0.f, 0.f);
#pragma unroll
    for (int j = 0; j < 8; ++j) acc = f4add(acc, base[j * 128 * 256]);
    lds4[t] = acc;  // index = slot*8 + col4
  }
  __syncthreads();
  if (t < 512) lds4[t] = f4add(lds4[t], lds4[t + 512]);
  __syncthreads();
  if (t < 256) lds4[t] = f4add(lds4[t], lds4[t + 256]);
  __syncthreads();
  if (t < 128) lds4[t] = f4add(lds4[t], lds4[t + 128]);
  __syncthreads();
  if (t < 64) lds4[t] = f4add(lds4[t], lds4[t + 64]);
  __syncthreads();
  if (t < 32) lds4[t] = f4add(lds4[t], lds4[t + 32]);
  __syncthreads();
  if (t < 16) lds4[t] = f4add(lds4[t], lds4[t + 16]);
  __syncthreads();
  if (t < 8) {
    float4 s = f4add(lds4[t], lds4[t + 8]);
    ((float4*)(ws + WS_PARTIAL))[chunk * 256 + stripe * 8 + t] = s;
  }
  if (t < 32) out_attn[blk * 32 + t] = 1.f / 8192.f;  // softmax(const) exact
  const int w = t >> 6, l = t & 63;
  if (w < 4) {
    const int i = blk * 4 + w;  // 0..1023
    const int tok = token[0];
    const float4* emb4 = (const float4*)embedding + (size_t)tok * 256;
    const float4* cw4 = (const float4*)comb_w + (size_t)i * 512;  // first half
    float acc = dot4(cw4[l], emb4[l]) + dot4(cw4[64 + l], emb4[64 + l]) +
                dot4(cw4[128 + l], emb4[128 + l]) + dot4(cw4[192 + l], emb4[192 + l]);
    acc = wred(acc);
    if (l == 0) ws[WS_CEMB + i] = acc + comb_b[i];
  }
}

// K2 (256 blocks x 1024): block-specialized:
//   blk<192 : gh row r = blk*16 + w  (one 4KB row per wave)
//   192..255: x rows — block redundantly reduces the 8 column-partials
//             (32 KB L2) into LDS aa, then 16 waves each do one row:
//             x[i] = relu(cemb[i] + comb_w[i, H:] @ aa)
__global__ __launch_bounds__(1024) void k2_mid(
    const float* __restrict__ w_hh, const float* __restrict__ hidden,
    const float* __restrict__ comb_w, float* __restrict__ ws) {
  const int blk = blockIdx.x, t = threadIdx.x;
  const int w = t >> 6, l = t & 63;
  if (blk < 192) {
    const int r = blk * 16 + w;  // 0..3071
    const float4* h4 = (const float4*)hidden;
    const float4* m4 = (const float4*)w_hh + (size_t)r * 256;
    float acc = dot4(m4[l], h4[l]) + dot4(m4[64 + l], h4[64 + l]) +
                dot4(m4[128 + l], h4[128 + l]) + dot4(m4[192 + l], h4[192 + l]);
    acc = wred(acc);
    if (l == 0) ws[WS_GH + r] = acc;
  } else {
    __shared__ float aas[1024];
    float s = 0.f;
#pragma unroll
    for (int j = 0; j < 8; ++j) s += ws[WS_PARTIAL + j * 1024 + t];
    aas[t] = s * (1.f / 8192.f);
    __syncthreads();
    const int i = (blk - 192) * 16 + w;  // 0..1023
    const float4* aa4 = (const float4*)aas;
    const float4* cw4 = (const float4*)comb_w + (size_t)i * 512 + 256;  // 2nd half
    float acc = dot4(cw4[l], aa4[l]) + dot4(cw4[64 + l], aa4[64 + l]) +
                dot4(cw4[128 + l], aa4[128 + l]) + dot4(cw4[192 + l], aa4[192 + l]);
    acc = wred(acc);
    if (l == 0) ws[WS_X + i] = fmaxf(ws[WS_CEMB + i] + acc, 0.f);
  }
}

// K4 (256 blocks x 256): wave computes all 3 gi rows for its i, then lane 0
// applies GRU gate math -> h_new.
__global__ void k4_gates_h(const float* __restrict__ w_ih,
                           const float* __restrict__ b_ih, const float* __restrict__ b_hh,
                           const float* __restrict__ hidden, float* __restrict__ ws,
                           float* __restrict__ d_out) {
  const int w = threadIdx.x >> 6, l = threadIdx.x & 63;
  const int i = blockIdx.x * 4 + w;  // 0..1023
  const float4* x4 = (const float4*)(ws + WS_X);
  float4 xv0 = x4[l], xv1 = x4[64 + l], xv2 = x4[128 + l], xv3 = x4[192 + l];
  const float4* m0 = (const float4*)w_ih + (size_t)i * 256;
  const float4* m1 = (const float4*)w_ih + (size_t)(i + 1024) * 256;
  const float4* m2 = (const float4*)w_ih + (size_t)(i + 2048) * 256;
  float a0 = dot4(m0[l], xv0) + dot4(m0[64 + l], xv1) +
             dot4(m0[128 + l], xv2) + dot4(m0[192 + l], xv3);
  float a1 = dot4(m1[l], xv0) + dot4(m1[64 + l], xv1) +
             dot4(m1[128 + l], xv2) + dot4(m1[192 + l], xv3);
  float a2 = dot4(m2[l], xv0) + dot4(m2[64 + l], xv1) +
             dot4(m2[128 + l], xv2) + dot4(m2[192 + l], xv3);
  a0 = wred(a0); a1 = wred(a1); a2 = wred(a2);
  if (l == 0) {
    float ir = a0 + b_ih[i];
    float iz = a1 + b_ih[i + 1024];
    float inn = a2 + b_ih[i + 2048];
    float hr = ws[WS_GH + i] + b_hh[i];
    float hz = ws[WS_GH + i + 1024] + b_hh[i + 1024];
    float hn = ws[WS_GH + i + 2048] + b_hh[i + 2048];
    float rg = 1.f / (1.f + expf(-(ir + hr)));
    float zg = 1.f / (1.f + expf(-(iz + hz)));
    float ng = tanhf(inn + rg * hn);
    float h = (1.f - zg) * ng + zg * hidden[i];
    ws[WS_HNEW + i] = h;
    d_out[VN + i] = h;  // h_new output region
  }
}

// K5 (2048 blocks x 256 = 8192 waves, exactly 8 blocks/CU): logits GEMV,
// 2 iters x 3-row ILP at stride 8192 (device-instantaneous contiguity),
// tail row gw+49152 for gw<1105. Per-block exp partials in fixed order.
__global__ void k5_logits(const float* __restrict__ out_w, const float* __restrict__ out_b,
                          float* __restrict__ ws) {
  const int blk = blockIdx.x, t = threadIdx.x;
  const int w = t >> 6, l = t & 63;
  const int gw = blk * 4 + w;  // 0..8191
  const float4* h4p = (const float4*)(ws + WS_HNEW);
  float4 h0_ = h4p[l], h1_ = h4p[64 + l], h2_ = h4p[128 + l], h3_ = h4p[192 + l];
  const float4* ow4 = (const float4*)out_w;
  double eacc = 0.0;
  // iter 0: rows gw, gw+8192, gw+16384 (max 24575 < VN)
  // iter 1: rows gw+24576, gw+32768, gw+40960 (max 49151 < VN)
#pragma unroll
  for (int it = 0; it < 2; ++it) {
    const int v0 = gw + it * 24576, v1 = v0 + 8192, v2 = v0 + 16384;
    const float4* r0 = ow4 + (size_t)v0 * 256;
    const float4* r1 = ow4 + (size_t)v1 * 256;
    const float4* r2 = ow4 + (size_t)v2 * 256;
    float a0 = dot4(r0[l], h0_) + dot4(r0[64 + l], h1_) +
               dot4(r0[128 + l], h2_) + dot4(r0[192 + l], h3_);
    float a1 = dot4(r1[l], h0_) + dot4(r1[64 + l], h1_) +
               dot4(r1[128 + l], h2_) + dot4(r1[192 + l], h3_);
    float a2 = dot4(r2[l], h0_) + dot4(r2[64 + l], h1_) +
               dot4(r2[128 + l], h2_) + dot4(r2[192 + l], h3_);
    a0 = wred(a0); a1 = wred(a1); a2 = wred(a2);
    if (l == 0) {
      float lg0 = a0 + out_b[v0];
      float lg1 = a1 + out_b[v1];
      float lg2 = a2 + out_b[v2];
      ws[WS_LOGITS + v0] = lg0;
      ws[WS_LOGITS + v1] = lg1;
      ws[WS_LOGITS + v2] = lg2;
      eacc += (double)expf(lg0) + (double)expf(lg1) + (double)expf(lg2);
    }
  }
  if (gw < 1105) {  // tail rows 49152..50256
    const int v = gw + 49152;
    const float4* r0 = ow4 + (size_t)v * 256;
    float a = dot4(r0[l], h0_) + dot4(r0[64 + l], h1_) +
              dot4(r0[128 + l], h2_) + dot4(r0[192 + l], h3_);
    a = wred(a);
    if (l == 0) {
      float lg = a + out_b[v];
      ws[WS_LOGITS + v] = lg;
      eacc += (double)expf(lg);
    }
  }
  __shared__ double sd[4];
  if (l == 0) sd[w] = eacc;
  __syncthreads();
  if (t == 0) ((double*)(ws + WS_EXPD))[blk] = sd[0] + sd[1] + sd[2] + sd[3];
}

// K6: redundant deterministic logZ (fixed-order reduce of 2048 doubles) + subtract
__global__ void k6_final(const float* __restrict__ ws, float* __restrict__ d_out) {
  __shared__ double sd[256];
  const int t = threadIdx.x;
  const double* ed = (const double*)(ws + WS_EXPD);
  double a = 0.0;
#pragma unroll
  for (int j = 0; j < 8; ++j) a += ed[t + j * 256];
  sd[t] = a;
  __syncthreads();
  for (int s = 128; s; s >>= 1) {
    if (t < s) sd[t] += sd[t + s];
    __syncthreads();
  }
  const float logZ = (float)log(sd[0]);
  const int v = blockIdx.x * 256 + t;
  if (v < VN) d_out[v] = ws[WS_LOGITS + v] - logZ;
}

extern "C" void kernel_launch(void* const* d_in, const int* in_sizes, int n_in,
                              void* d_out, int out_size, void* d_ws, size_t ws_size,
                              hipStream_t stream) {
  const int* token = (const int*)d_in[0];
  const float* hidden = (const float*)d_in[1];
  const float* enc = (const float*)d_in[2];
  const float* embedding = (const float*)d_in[3];
  // d_in[4] attn_w, d_in[5] attn_b unused: softmax(broadcast(scalar)) is uniform
  const float* comb_w = (const float*)d_in[6];
  const float* comb_b = (const float*)d_in[7];
  const float* w_ih = (const float*)d_in[8];
  const float* w_hh = (const float*)d_in[9];
  const float* b_ih = (const float*)d_in[10];
  const float* b_hh = (const float*)d_in[11];
  const float* out_w = (const float*)d_in[12];
  const float* out_b = (const float*)d_in[13];
  float* out = (float*)d_out;
  float* ws = (float*)d_ws;

  k1_front<<<256, 1024, 0, stream>>>(enc, token, embedding, comb_w, comb_b,
                                     ws, out + VN + HN);
  k2_mid<<<256, 1024, 0, stream>>>(w_hh, hidden, comb_w, ws);
  k4_gates_h<<<256, 256, 0, stream>>>(w_ih, b_ih, b_hh, hidden, ws, out);
  k5_logits<<<2048, 256, 0, stream>>>(out_w, out_b, ws);
  k6_final<<<197, 256, 0, stream>>>(ws, out);
}